// Round 8
// baseline (590.743 us; speedup 1.0000x reference)
//
#include <hip/hip_runtime.h>

#define NE 11
#define NP 64
#define NC 128
#define NHW 4096
#define NHID 512

typedef __attribute__((ext_vector_type(8))) __bf16 bf16x8;
typedef __attribute__((ext_vector_type(4))) __bf16 bf16x4;
typedef __attribute__((ext_vector_type(4))) float f32x4;

#if __has_builtin(__builtin_amdgcn_exp2f)
#define FEXP2(x) __builtin_amdgcn_exp2f(x)
#else
#define FEXP2(x) exp2f(x)
#endif
#if __has_builtin(__builtin_amdgcn_rcpf)
#define FRCP(x) __builtin_amdgcn_rcpf(x)
#else
#define FRCP(x) (1.0f / (x))
#endif

__device__ __forceinline__ unsigned short f2bf(float f) {
    return __builtin_bit_cast(unsigned short, (__bf16)f);
}

// Exact-to-1.5e-7 gelu via A&S 7.1.26 erf polynomial, branchless.
__device__ __forceinline__ float gelu_erf(float v) {
    float av = fabsf(v);
    float z = av * 0.70710678118654752440f;
    float t = FRCP(fmaf(z, 0.3275911f, 1.0f));
    float p = t * fmaf(t, fmaf(t, fmaf(t, fmaf(t, 1.061405429f, -1.453152027f),
                                       1.421413741f), -0.284496736f), 0.254829592f);
    float e = FEXP2(z * z * -1.44269504088896f); // exp(-z^2)
    float erfz = fmaf(-p, e, 1.0f);
    float hv = 0.5f * av;
    float g = fmaf(hv, erfz, hv);
    return g + fminf(v, 0.0f);
}

// LDS B-fragment read: row-major [row][128] bf16 tile, XOR-swizzled
__device__ __forceinline__ bf16x8 ldsB(const char* base, int row, int col) {
    int off = ((row << 8) + (col << 1)) ^ ((row & 7) << 4);
    return *(const bf16x8*)(base + off);
}

// ---------------- kernel 1: weight cvt + global pool ----------------
__global__ void k_prep(const float* __restrict__ ew1, const float* __restrict__ ew2,
                       unsigned short* __restrict__ o1, unsigned short* __restrict__ o2,
                       const float* __restrict__ x, float* __restrict__ gc) {
    if (blockIdx.x < 512) {
        const int n = NE * NHID * NC;
        for (int i = blockIdx.x * 256 + threadIdx.x; i < n; i += 512 * 256) {
            o1[i] = f2bf(ew1[i]);
            o2[i] = f2bf(ew2[i]);
        }
    } else {
        int row = blockIdx.x - 512; // b*128+c
        const float* p = x + (size_t)row * NHW;
        float s = 0.f;
        for (int i = threadIdx.x; i < NHW; i += 256) s += p[i];
        __shared__ float red[256];
        red[threadIdx.x] = s;
        __syncthreads();
        for (int off = 128; off > 0; off >>= 1) {
            if (threadIdx.x < off) red[threadIdx.x] += red[threadIdx.x + off];
            __syncthreads();
        }
        if (threadIdx.x == 0) gc[row] = red[0] * (1.0f / 4096.0f);
    }
}

// ---------------- kernel 2: tiny attention path + ortho + stat zero ----------------
__global__ void k_attn(const float* __restrict__ gc, const float* __restrict__ proto,
                       const float* __restrict__ ctx_w, const float* __restrict__ ctx_b,
                       const float* __restrict__ wq, const float* __restrict__ bq,
                       const float* __restrict__ wk, const float* __restrict__ bk,
                       const float* __restrict__ wv, const float* __restrict__ bv,
                       const float* __restrict__ wo, const float* __restrict__ bo,
                       const float* __restrict__ lng, const float* __restrict__ lnb,
                       float* __restrict__ up, float* __restrict__ ortho, float* __restrict__ stats) {
    int t = threadIdx.x;
    __shared__ float seq[12][64], qs[12][64], ks_[12][64], vs[12][64], ao[12][64], rr[12][64];
    __shared__ float nr[NE], sq[NE * NE];

    if (blockIdx.x == 8) {
        if (t < 22) stats[t] = 0.0f;
        if (t < NE) {
            float s = 0.f;
            for (int p = 0; p < NP; p++) { float v = proto[t * NP + p]; s += v * v; }
            nr[t] = rsqrtf(s);
        }
        __syncthreads();
        if (t < NE * NE) {
            int i = t / NE, j = t % NE;
            float d = 0.f;
            for (int p = 0; p < NP; p++) d += proto[i * NP + p] * proto[j * NP + p];
            float c = d * nr[i] * nr[j] - (i == j ? 1.0f : 0.0f);
            sq[t] = c * c;
        }
        __syncthreads();
        if (t == 0) {
            float s = 0.f;
            for (int i = 0; i < NE * NE; i++) s += sq[i];
            *ortho = sqrtf(s);
        }
        return;
    }

    int b = blockIdx.x;
    if (t < NP) {
        float a = ctx_b[t];
        for (int c = 0; c < NC; c++) a = fmaf(gc[b * NC + c], ctx_w[t * NC + c], a);
        seq[0][t] = a;
    }
    for (int i = t; i < NE * NP; i += 256) { int e = i >> 6, p = i & 63; seq[e + 1][p] = proto[e * NP + p]; }
    __syncthreads();
    for (int i = t; i < 12 * NP; i += 256) {
        int s = i >> 6, p = i & 63;
        float aq = bq[p], ak = bk[p], av = bv[p];
        for (int pp = 0; pp < NP; pp++) {
            float sv = seq[s][pp];
            aq = fmaf(sv, wq[p * NP + pp], aq);
            ak = fmaf(sv, wk[p * NP + pp], ak);
            av = fmaf(sv, wv[p * NP + pp], av);
        }
        qs[s][p] = aq; ks_[s][p] = ak; vs[s][p] = av;
    }
    __syncthreads();
    if (t < 48) {
        int h = t / 12, qq = t % 12;
        float sc[12], m = -1e30f;
        for (int kk = 0; kk < 12; kk++) {
            float s = 0.f;
            for (int d = 0; d < 16; d++) s = fmaf(qs[qq][h * 16 + d], ks_[kk][h * 16 + d], s);
            s *= 0.25f;
            sc[kk] = s;
            if (s > m) m = s;
        }
        float den = 0.f;
        for (int kk = 0; kk < 12; kk++) { sc[kk] = expf(sc[kk] - m); den += sc[kk]; }
        float inv = 1.0f / den;
        for (int d = 0; d < 16; d++) {
            float a = 0.f;
            for (int kk = 0; kk < 12; kk++) a = fmaf(sc[kk], vs[kk][h * 16 + d], a);
            ao[qq][h * 16 + d] = a * inv;
        }
    }
    __syncthreads();
    for (int i = t; i < 12 * NP; i += 256) {
        int s = i >> 6, p = i & 63;
        float a = bo[p];
        for (int pp = 0; pp < NP; pp++) a = fmaf(ao[s][pp], wo[p * NP + pp], a);
        rr[s][p] = a + seq[s][p];
    }
    __syncthreads();
    if (t < 12) {
        int s = t;
        float m = 0.f;
        for (int p = 0; p < NP; p++) m += rr[s][p];
        m *= (1.0f / 64.0f);
        float v = 0.f;
        for (int p = 0; p < NP; p++) { float d = rr[s][p] - m; v += d * d; }
        v *= (1.0f / 64.0f);
        float is = rsqrtf(v + 1e-5f);
        if (s >= 1)
            for (int p = 0; p < NP; p++)
                up[(b * NE + s - 1) * NP + p] = (rr[s][p] - m) * is * lng[p] + lnb[p];
    }
}

// ---------------- kernel 3: fused gating + barrier-free MoE experts ----------------
// 4 waves/block, 64 px/block. wave = (pgrp = px-half, ws = o-half).
// Expert loop is register-only: x B-frags hoisted to VGPRs, h transposed
// D-frag -> B-frag via 8 __shfl per tile (intra-wave), weights streamed from L2.
__global__ __launch_bounds__(256, 2) void k_main(
    const float* __restrict__ x, const float* __restrict__ inp_w, const float* __restrict__ inp_b,
    const unsigned short* __restrict__ ew1b, const float* __restrict__ eb1,
    const unsigned short* __restrict__ ew2b, const float* __restrict__ eb2,
    const float* __restrict__ upw, float* __restrict__ stats, float* __restrict__ out) {
    int tid = threadIdx.x;
    int bimg = blockIdx.x >> 6;
    int pix0 = (blockIdx.x & 63) << 6; // 64 pixels per block
    int wid = tid >> 6;                // 0..3
    int lane = tid & 63;
    int l15 = tid & 15;
    int l4 = (tid >> 4) & 3;
    int ws = wid & 1;   // o-half (0: ob 0-7, 1: ob 8-15)
    int pgrp = wid >> 1; // px group (32 px each)
    int wpx0 = pgrp << 5;

    // LDS: xs @0 (16K) | stage @16384 (8K) | lpart @24576 (11K) | upl @35840 | wm @38656
    // reduce scratch reuses @0 (pgrp0) and @16384 (pgrp1), 16K each; wm/upl survive.
    __shared__ __align__(16) char smem[41472];
    char* xs = smem;
    float* stage = (float*)(smem + 16384);
    float* lpart = (float*)(smem + 24576);
    float* upl = (float*)(smem + 35840);
    float* wm = (float*)(smem + 38656);

    // ---- phase 0: stage x (bf16 swizzled) + fp32 gating (round-1-proven structure) ----
    for (int i = tid; i < NE * NP; i += 256) upl[i] = upw[bimg * (NE * NP) + i];
    int pg = wid; // p-range pg*16..pg*16+15
    int pixl = tid & 63;
    float xr[16];
#pragma unroll
    for (int p = 0; p < 16; p++) xr[p] = inp_b[pg * 16 + p];

    for (int cb = 0; cb < NC; cb += 32) {
        for (int i = tid; i < 32 * 64; i += 256) {
            int cc = i >> 6, px = i & 63;
            float v = x[(size_t)(bimg * NC + cb + cc) * NHW + pix0 + px];
            stage[cc * 64 + px] = v;
            int off = ((px << 8) + ((cb + cc) << 1)) ^ ((px & 7) << 4);
            *(unsigned short*)(xs + off) = f2bf(v);
        }
        __syncthreads();
#pragma unroll 4
        for (int cc = 0; cc < 32; cc++) {
            float xv = stage[cc * 64 + pixl];
#pragma unroll
            for (int p = 0; p < 16; p++)
                xr[p] = fmaf(inp_w[(pg * 16 + p) * NC + cb + cc], xv, xr[p]);
        }
        __syncthreads();
    }
#pragma unroll
    for (int e = 0; e < NE; e++) {
        float a = 0.f;
#pragma unroll
        for (int p = 0; p < 16; p++) a = fmaf(upl[e * NP + pg * 16 + p], xr[p], a);
        lpart[(pg * NE + e) * 64 + pixl] = a;
    }
    __syncthreads();

    // per-pixel softmax + top-6 (fp32 exact), stats via shuffle/ballot (wave 0)
    if (tid < 64) {
        float pr[NE];
        float mx = -1e30f;
#pragma unroll
        for (int e = 0; e < NE; e++) {
            float l = (lpart[(0 * NE + e) * 64 + tid] + lpart[(1 * NE + e) * 64 + tid] +
                       lpart[(2 * NE + e) * 64 + tid] + lpart[(3 * NE + e) * 64 + tid]) * 0.125f;
            pr[e] = l;
            mx = fmaxf(mx, l);
        }
        float den = 0.f;
#pragma unroll
        for (int e = 0; e < NE; e++) { pr[e] = __expf(pr[e] - mx); den += pr[e]; }
        float inv = 1.0f / den;
#pragma unroll
        for (int e = 0; e < NE; e++) pr[e] *= inv;
        unsigned used = 0;
        float tvsum = 0.f;
        for (int k = 0; k < 6; k++) { // strict > keeps lowest index on ties
            float bv = -1.f;
            int best = 0;
#pragma unroll
            for (int e = 0; e < NE; e++) {
                bool sel = !((used >> e) & 1) && (pr[e] > bv);
                bv = sel ? pr[e] : bv;
                best = sel ? e : best;
            }
            used |= 1u << best;
            tvsum += bv;
        }
        float itv = 1.0f / tvsum;
#pragma unroll
        for (int e = 0; e < NE; e++)
            wm[e * 64 + tid] = ((used >> e) & 1) ? pr[e] * itv : 0.0f;
#pragma unroll
        for (int e = 0; e < NE; e++) {
            float s = pr[e];
            for (int off = 32; off; off >>= 1) s += __shfl_xor(s, off);
            unsigned long long bal = __ballot((used >> e) & 1);
            if (tid == 0) {
                atomicAdd(&stats[e], s);
                atomicAdd(&stats[NE + e], (float)__popcll(bal));
            }
        }
    }
    __syncthreads();

    // ---- hoist x B-frags into registers (reused by all 88 o-blocks) ----
    bf16x8 xb[2][4];
#pragma unroll
    for (int nt = 0; nt < 2; nt++)
#pragma unroll
        for (int ksp = 0; ksp < 4; ksp++)
            xb[nt][ksp] = ldsB(xs, wpx0 + nt * 16 + l15, ksp * 32 + l4 * 8);

    // shfl source lanes for the h D->B transpose (constant per thread)
    int sA = l15 + 16 * (2 * (l4 & 1));
    int sB = sA + 16;
    bool hi = (l4 >= 2);

    // ---- expert loop: ZERO barriers, register-only ----
    f32x4 acc2[8][2];
#pragma unroll
    for (int ct = 0; ct < 8; ct++)
#pragma unroll
        for (int nt = 0; nt < 2; nt++) acc2[ct][nt] = {0.f, 0.f, 0.f, 0.f};

    for (int e = 0; e < NE; e++) {
        float wg[2];
        wg[0] = wm[e * 64 + wpx0 + l15];
        wg[1] = wm[e * 64 + wpx0 + 16 + l15];
        const unsigned short* w1e = ew1b + (size_t)e * NHID * NC;
        const unsigned short* w2e = ew2b + (size_t)e * NC * NHID;
        const float* b1e = eb1 + e * NHID;
        for (int obl = 0; obl < 8; obl++) {
            int o0 = (ws * 8 + obl) * 32;
            // layer-1 A frags (w1[o][c]) from L2
            bf16x8 a1[2][4];
#pragma unroll
            for (int m = 0; m < 2; m++)
#pragma unroll
                for (int ksp = 0; ksp < 4; ksp++)
                    a1[m][ksp] = *(const bf16x8*)(w1e + (size_t)(o0 + m * 16 + l15) * NC + ksp * 32 + l4 * 8);
            f32x4 acc1[2][2];
#pragma unroll
            for (int m = 0; m < 2; m++)
#pragma unroll
                for (int nt = 0; nt < 2; nt++) acc1[m][nt] = {0.f, 0.f, 0.f, 0.f};
#pragma unroll
            for (int m = 0; m < 2; m++)
#pragma unroll
                for (int nt = 0; nt < 2; nt++)
#pragma unroll
                    for (int ksp = 0; ksp < 4; ksp++)
                        acc1[m][nt] = __builtin_amdgcn_mfma_f32_16x16x32_bf16(a1[m][ksp], xb[nt][ksp],
                                                                              acc1[m][nt], 0, 0, 0);
            // bias + gelu + gate fold -> packed bf16 pairs p[nt][m] = (uint2)
            f32x4 b1[2];
#pragma unroll
            for (int m = 0; m < 2; m++) b1[m] = *(const f32x4*)(b1e + o0 + m * 16 + l4 * 4);
            uint2 pk[2][2];
#pragma unroll
            for (int nt = 0; nt < 2; nt++)
#pragma unroll
                for (int m = 0; m < 2; m++) {
                    bf16x4 hb;
#pragma unroll
                    for (int r = 0; r < 4; r++)
                        hb[r] = (__bf16)(gelu_erf(acc1[m][nt][r] + b1[m][r]) * wg[nt]);
                    pk[nt][m] = __builtin_bit_cast(uint2, hb);
                }
            // D-frag -> B-frag transpose via 8 shfl per nt (intra-wave)
            bf16x8 hbf[2];
#pragma unroll
            for (int nt = 0; nt < 2; nt++) {
                unsigned a0a = __shfl((int)pk[nt][0].x, sA);
                unsigned a1a = __shfl((int)pk[nt][0].y, sA);
                unsigned a0b = __shfl((int)pk[nt][0].x, sB);
                unsigned a1b = __shfl((int)pk[nt][0].y, sB);
                unsigned b0a = __shfl((int)pk[nt][1].x, sA);
                unsigned b1a = __shfl((int)pk[nt][1].y, sA);
                unsigned b0b = __shfl((int)pk[nt][1].x, sB);
                unsigned b1b = __shfl((int)pk[nt][1].y, sB);
                uint4 q;
                q.x = hi ? b0a : a0a;
                q.y = hi ? b1a : a1a;
                q.z = hi ? b0b : a0b;
                q.w = hi ? b1b : a1b;
                hbf[nt] = __builtin_bit_cast(bf16x8, q);
            }
            // layer-2: A = w2[c][o-slice] from L2, B = hbf; accumulate all 8 c-tiles
            bf16x8 a2f[8];
#pragma unroll
            for (int ct = 0; ct < 8; ct++)
                a2f[ct] = *(const bf16x8*)(w2e + (size_t)(ct * 16 + l15) * NHID + o0 + l4 * 8);
#pragma unroll
            for (int ct = 0; ct < 8; ct++)
#pragma unroll
                for (int nt = 0; nt < 2; nt++)
                    acc2[ct][nt] = __builtin_amdgcn_mfma_f32_16x16x32_bf16(a2f[ct], hbf[nt],
                                                                           acc2[ct][nt], 0, 0, 0);
        }
    }

    // ---- reduce o-halves via LDS (xs/stage regions are dead), then epilogue ----
    float* scr = (float*)(smem + pgrp * 16384);
    __syncthreads(); // all waves done with expert loop (and xs reads long done)
    if (ws == 1) {
#pragma unroll
        for (int ct = 0; ct < 8; ct++)
#pragma unroll
            for (int nt = 0; nt < 2; nt++) {
                int off = (((ct * 2 + nt) * 16) ^ ((lane & 7) << 4)) >> 2;
                *(f32x4*)(scr + lane * 64 + off) = acc2[ct][nt];
            }
    }
    __syncthreads();
    if (ws == 0) {
#pragma unroll
        for (int ct = 0; ct < 8; ct++)
#pragma unroll
            for (int nt = 0; nt < 2; nt++) {
                int off = (((ct * 2 + nt) * 16) ^ ((lane & 7) << 4)) >> 2;
                f32x4 o = *(const f32x4*)(scr + lane * 64 + off);
#pragma unroll
                for (int r = 0; r < 4; r++) acc2[ct][nt][r] += o[r];
            }
        // add sum_e w_e * eb2
#pragma unroll
        for (int e = 0; e < NE; e++) {
            float wg0 = wm[e * 64 + wpx0 + l15];
            float wg1 = wm[e * 64 + wpx0 + 16 + l15];
#pragma unroll
            for (int ct = 0; ct < 8; ct++) {
                f32x4 b2 = *(const f32x4*)(eb2 + e * NC + ct * 16 + l4 * 4);
#pragma unroll
                for (int r = 0; r < 4; r++) {
                    acc2[ct][0][r] = fmaf(wg0, b2[r], acc2[ct][0][r]);
                    acc2[ct][1][r] = fmaf(wg1, b2[r], acc2[ct][1][r]);
                }
            }
        }
        // out = x + final
#pragma unroll
        for (int ct = 0; ct < 8; ct++)
#pragma unroll
            for (int nt = 0; nt < 2; nt++) {
                int px = pix0 + wpx0 + nt * 16 + l15;
#pragma unroll
                for (int r = 0; r < 4; r++) {
                    int c = ct * 16 + l4 * 4 + r;
                    size_t g = (size_t)(bimg * NC + c) * NHW + px;
                    out[g] = x[g] + acc2[ct][nt][r];
                }
            }
    }
}

// ---------------- kernel 4: aux scalar ----------------
__global__ void k_final(const float* __restrict__ stats, const float* __restrict__ ortho,
                        float* __restrict__ out) {
    if (threadIdx.x == 0 && blockIdx.x == 0) {
        float aux = 0.f;
        for (int e = 0; e < NE; e++)
            aux += (stats[e] * (1.0f / 32768.0f)) * (stats[NE + e] * (1.0f / 32768.0f));
        aux *= (float)NE;
        out[4194304] = aux + 0.5f * (*ortho);
    }
}

extern "C" void kernel_launch(void* const* d_in, const int* in_sizes, int n_in,
                              void* d_out, int out_size, void* d_ws, size_t ws_size,
                              hipStream_t stream) {
    const float* x = (const float*)d_in[0];
    const float* proto = (const float*)d_in[1];
    const float* ctx_w = (const float*)d_in[2];
    const float* ctx_b = (const float*)d_in[3];
    const float* inp_w = (const float*)d_in[4];
    const float* inp_b = (const float*)d_in[5];
    const float* wq = (const float*)d_in[6];
    const float* bq = (const float*)d_in[7];
    const float* wk = (const float*)d_in[8];
    const float* bk = (const float*)d_in[9];
    const float* wv = (const float*)d_in[10];
    const float* bv = (const float*)d_in[11];
    const float* wo = (const float*)d_in[12];
    const float* bo = (const float*)d_in[13];
    const float* lng = (const float*)d_in[14];
    const float* lnb = (const float*)d_in[15];
    const float* ew1 = (const float*)d_in[16];
    const float* eb1 = (const float*)d_in[17];
    const float* ew2 = (const float*)d_in[18];
    const float* eb2 = (const float*)d_in[19];
    float* out = (float*)d_out;
    float* ws = (float*)d_ws;

    float* gc = ws;           // 1024 floats
    float* up = ws + 1024;    // 8*11*64 = 5632
    float* ortho = ws + 6656; // 1
    float* stats = ws + 6657; // 22
    unsigned short* ew1b = (unsigned short*)(ws + 8192); // 720896 ushorts
    unsigned short* ew2b = ew1b + NE * NHID * NC;        // 720896 ushorts

    k_prep<<<1536, 256, 0, stream>>>(ew1, ew2, ew1b, ew2b, x, gc);
    k_attn<<<9, 256, 0, stream>>>(gc, proto, ctx_w, ctx_b, wq, bq, wk, bk, wv, bv, wo, bo, lng, lnb,
                                  up, ortho, stats);
    k_main<<<512, 256, 0, stream>>>(x, inp_w, inp_b, ew1b, eb1, ew2b, eb2, up, stats, out);
    k_final<<<1, 64, 0, stream>>>(stats, ortho, out);
}